// Round 10
// baseline (69.408 us; speedup 1.0000x reference)
//
#include <hip/hip_runtime.h>

#define BB 512
#define TT 30
#define HH 41
#define WFW 40
#define NSEC 9
#define SECLEN 4
#define NF 50
#define KH 6
#define THRESH 23.0f
#define NBT (BB*TT)                 // 15360 (b,t) rows
#define WIN_CNT (NSEC*BB)           // 4608 winners precede pots in d_out
#define NT_TILE 6                   // t-rows per block
#define TPB 5                       // tiles per batch (5*6 = 30)
#define ROWF (HH*WFW)               // 1640 floats per (b,t) row
#define SLAB_B 3360                 // bytes/slab: 1680 bf16 (1640 data + pad); pad never read
#define XBYTES (NT_TILE*SLAB_B)     // 20160
#define NFRAG (NSEC*2*15)           // 270 B-fragments (i, Nt, ks)
#define WSW_BYTES (NFRAG*64*16)     // 276480
#define MASK_BYTES (NSEC*BB*TPB*64*4) // 5898240: u32 6-bit masks [i][b][tp][f64]

typedef __attribute__((ext_vector_type(8)))  short short8;   // 8 bf16 = 4 VGPR
typedef __attribute__((ext_vector_type(16))) float f32x16;   // 32x32 acc

// ---------------------------------------------------------------------------
// Pre-kernel: W fp32 -> bf16 B-fragments for mfma_f32_32x32x16_bf16.
// Fragment (i,Nt,ks): lane l holds B[k][f], f = Nt*32+(l&31), k = ks*16 +
// (l>>5)*8 + j. Zero for f>=50. K=240 exact. (Verified passing in R9.)
// ---------------------------------------------------------------------------
__global__ __launch_bounds__(256) void wconv_kernel(const float* __restrict__ W,
                                                    unsigned char* __restrict__ wsw)
{
    int gid  = blockIdx.x * 256 + threadIdx.x;
    int frag = gid >> 6, l = gid & 63;
    if (frag >= NFRAG) return;
    int i   = frag / 30, rem = frag - i * 30;
    int Nt  = rem / 15,  ks  = rem - Nt * 15;
    int f   = Nt * 32 + (l & 31);
    int kb  = ks * 16 + (l >> 5) * 8;
    unsigned d0 = 0, d1 = 0, d2 = 0, d3 = 0;
    if (f < NF) {
        const float* src = W + (size_t)(i * NF + f) * (KH * WFW) + kb;
        float4 v0 = ((const float4*)src)[0];
        float4 v1 = ((const float4*)src)[1];
        float vv[8] = {v0.x, v0.y, v0.z, v0.w, v1.x, v1.y, v1.z, v1.w};
        unsigned r[8];
        #pragma unroll
        for (int j = 0; j < 8; ++j) {
            unsigned a = __float_as_uint(vv[j]);
            r[j] = (a + 0x7FFFu + ((a >> 16) & 1u)) >> 16;   // RNE to bf16
        }
        d0 = r[0] | (r[1] << 16); d1 = r[2] | (r[3] << 16);
        d2 = r[4] | (r[5] << 16); d3 = r[6] | (r[7] << 16);
    }
    ((uint4*)wsw)[(size_t)frag * 64 + l] = make_uint4(d0, d1, d2, d3);
}

// ---------------------------------------------------------------------------
// Main kernel: block = (batch b, t-part tp) = 6 t-rows, ALL 9 sections.
// SMALL blocks (128 thr, 20.2 KB LDS) -> 7 blocks/CU: co-resident blocks
// de-phase so stage (HBM) / compute (L2+LDS+MFMA) / store overlap chip-wide.
// Wave = Nt (2 waves). M = 6t*4s = 24 rows in one 32x32 tile (rq=3 unused).
// Winners fused: per-(i,Nt,rq) ballot -> LDS -> 6-bit mask per (i,f).
// ---------------------------------------------------------------------------
template<bool WRITE_MASK>
__global__ __launch_bounds__(128, 4) void pots_mfma(const float* __restrict__ x,
                                                    const unsigned char* __restrict__ wsw,
                                                    float* __restrict__ out,
                                                    unsigned* __restrict__ msk)
{
    __shared__ alignas(16) unsigned char xs[XBYTES];            // 20160 B
    __shared__ unsigned long long wsc[NSEC * 2 * 3];            // 432 B
    const int tid = threadIdx.x;
    const int blk = blockIdx.x;                 // b*TPB + tp
    const int b   = blk / TPB, tp = blk - b * TPB;
    const int bt0 = b * TT + tp * NT_TILE;

    // ---- stage 6 full x rows (1640 floats each) -> bf16 slabs, coalesced --
    const float* xg = x + (size_t)bt0 * ROWF;
    #pragma unroll
    for (int it = 0; it < 20; ++it) {
        int idx = tid + it * 128;               // float4 index, 6*410 = 2460
        if (idx < NT_TILE * 410) {
            int r = idx / 410, pos = idx - r * 410;
            const float4 v = *(const float4*)(xg + (size_t)r * ROWF + pos * 4);
            unsigned u0 = __float_as_uint(v.x), u1 = __float_as_uint(v.y);
            unsigned u2 = __float_as_uint(v.z), u3 = __float_as_uint(v.w);
            uint2 p;                            // x in {0,1}: truncation exact
            p.x = (u0 >> 16) | (u1 & 0xFFFF0000u);
            p.y = (u2 >> 16) | (u3 & 0xFFFF0000u);
            *(uint2*)(xs + r * SLAB_B + pos * 8) = p;
        }
    }
    __syncthreads();

    const int l   = tid & 63;
    const int Nt  = tid >> 6;                   // wave = N-tile
    const int qp  = l >> 5;                     // k-half (A), t-parity (D)
    const int c31 = l & 31;
    const int ff  = Nt * 32 + c31;              // global f (D col)

    // A row m: rows 0..23 real; lanes 24..31 -> distinct dup rows 16..23
    // (their output rows land in rq=3, which is discarded).
    const int m = (c31 < 24) ? c31 : (c31 - 8);
    const unsigned abase = (unsigned)(m >> 2) * SLAB_B + (unsigned)(m & 3) * 80
                         + (unsigned)qp * 16;
    const unsigned char* wbN = wsw + (size_t)Nt * (15 * 1024) + (size_t)l * 16;
    float4* const pout = (float4*)(out + WIN_CNT);

    #pragma unroll
    for (int i = 0; i < NSEC; ++i) {
        const unsigned char* wbi = wbN + (size_t)i * (30 * 1024);
        const unsigned ib = (unsigned)i * 320;  // slab elem 160*i -> +320 B

        f32x16 acc = {0.f,0.f,0.f,0.f,0.f,0.f,0.f,0.f,
                      0.f,0.f,0.f,0.f,0.f,0.f,0.f,0.f};
        #pragma unroll
        for (int ks = 0; ks < 15; ++ks) {
            short8 bf = *(const short8*)(wbi + ks * 1024);
            short8 af = *(const short8*)(xs + abase + ib + ks * 32);
            acc = __builtin_amdgcn_mfma_f32_32x32x16_bf16(af, bf, acc, 0, 0, 0);
        }

        // D: col=c31 (f), row=(reg&3)+8*(reg>>2)+4*qp -> t_loc=2rq+qp, s=reg&3
        #pragma unroll
        for (int rq = 0; rq < 3; ++rq) {        // rq=3 -> rows 24..31: discarded
            const int t_loc = rq * 2 + qp;      // 0..5, always valid
            float m2 = fmaxf(fmaxf(acc[4*rq+0], acc[4*rq+1]),
                             fmaxf(acc[4*rq+2], acc[4*rq+3]));
            unsigned long long bal = __ballot(m2 >= THRESH);   // all 64 lanes
            if (WRITE_MASK && l == 0) wsc[(i * 2 + Nt) * 3 + rq] = bal;
            if (ff < NF) {
                size_t o = ((size_t)i * NBT + bt0 + t_loc) * NF + ff;
                pout[o] = make_float4(acc[4*rq+0], acc[4*rq+1],
                                      acc[4*rq+2], acc[4*rq+3]);
            }
        }
    }

    if (WRITE_MASK) {
        __syncthreads();
        // 6-bit t-mask per (i, f): bit t = 2rq+qp from ballot bit (qp*32 + fl)
        #pragma unroll
        for (int it = 0; it < 5; ++it) {
            int idx = tid + it * 128;           // 9*64 = 576 entries
            if (idx < NSEC * 64) {
                int i  = idx >> 6, f = idx & 63;
                int ng = f >> 5,  fl = f & 31;
                unsigned mres = 0;
                #pragma unroll
                for (int rq = 0; rq < 3; ++rq) {
                    unsigned long long w = wsc[(i * 2 + ng) * 3 + rq];
                    unsigned b0 = (unsigned)((w >> fl) & 1ULL);         // qp=0
                    unsigned b1 = (unsigned)((w >> (32 + fl)) & 1ULL);  // qp=1
                    mres |= (b0 << (2 * rq)) | (b1 << (2 * rq + 1));
                }
                msk[((size_t)(i * BB + b) * TPB + tp) * 64 + f] = mres;
            }
        }
    }
}

// ---------------------------------------------------------------------------
// Winners from 6-bit tile masks: 5 coalesced u32 loads per lane. Verified
// formula: c=popcnt, first=min(30-c,29), fv=bit(first),
// total=c*(fv+30*any(fv)), first-occurrence argmax, -1 if total<=0.
// ---------------------------------------------------------------------------
__global__ __launch_bounds__(64) void win_msk(const unsigned* __restrict__ msk,
                                              float* __restrict__ out)
{
    const int blk = blockIdx.x;              // i*BB + b
    const int f   = threadIdx.x;
    unsigned mask = 0u;
    #pragma unroll
    for (int tp = 0; tp < TPB; ++tp)
        mask |= msk[((size_t)blk * TPB + tp) * 64 + f] << (6 * tp);
    int c     = __popc(mask);
    int first = TT - c; if (first > TT - 1) first = TT - 1;
    int fv    = (f < NF) ? (int)((mask >> first) & 1u) : 0;
    unsigned long long bal = __ballot(fv != 0);
    int v30 = (bal != 0ull) ? TT : 0;
    int tot = (f < NF) ? c * (fv + v30) : -1;
    int idx = f;
    for (int off = 32; off > 0; off >>= 1) {
        int ot = __shfl_xor(tot, off);
        int oi = __shfl_xor(idx, off);
        if (ot > tot || (ot == tot && oi < idx)) { tot = ot; idx = oi; }
    }
    if (f == 0) out[blk] = (float)((tot > 0) ? idx : -1);
}

// Fallback: winners straight from pots (if ws too small for mask buffer).
__global__ __launch_bounds__(64) void win_pots(float* __restrict__ out)
{
    const int blk = blockIdx.x;
    const int f   = threadIdx.x;
    const float* po = out + WIN_CNT + (size_t)blk * TT * NF * SECLEN;
    unsigned mask = 0u;
    if (f < NF) {
        for (int t = 0; t < TT; ++t) {
            const float4 v = *(const float4*)(po + ((size_t)t * NF + f) * SECLEN);
            float m = fmaxf(fmaxf(v.x, v.y), fmaxf(v.z, v.w));
            if (m >= THRESH) mask |= (1u << t);
        }
    }
    int c     = __popc(mask);
    int first = TT - c; if (first > TT - 1) first = TT - 1;
    int fv    = (f < NF) ? (int)((mask >> first) & 1u) : 0;
    unsigned long long bal = __ballot(fv != 0);
    int v30 = (bal != 0ull) ? TT : 0;
    int tot = (f < NF) ? c * (fv + v30) : -1;
    int idx = f;
    for (int off = 32; off > 0; off >>= 1) {
        int ot = __shfl_xor(tot, off);
        int oi = __shfl_xor(idx, off);
        if (ot > tot || (ot == tot && oi < idx)) { tot = ot; idx = oi; }
    }
    if (f == 0) out[blk] = (float)((tot > 0) ? idx : -1);
}

extern "C" void kernel_launch(void* const* d_in, const int* in_sizes, int n_in,
                              void* d_out, int out_size, void* d_ws, size_t ws_size,
                              hipStream_t stream)
{
    const float* x = (const float*)d_in[0];
    const float* W = (const float*)d_in[1];
    float* out = (float*)d_out;
    unsigned char* wsw = (unsigned char*)d_ws;
    unsigned* msk = (unsigned*)(wsw + WSW_BYTES);
    const bool use_msk = ws_size >= (size_t)(WSW_BYTES + MASK_BYTES);

    wconv_kernel<<<(NFRAG * 64 + 255) / 256, 256, 0, stream>>>(W, wsw);
    if (use_msk) {
        pots_mfma<true><<<BB * TPB, 128, 0, stream>>>(x, wsw, out, msk);
        win_msk<<<NSEC * BB, 64, 0, stream>>>(msk, out);
    } else {
        pots_mfma<false><<<BB * TPB, 128, 0, stream>>>(x, wsw, out, nullptr);
        win_pots<<<NSEC * BB, 64, 0, stream>>>(out);
    }
}

// Round 11
// 52.425 us; speedup vs baseline: 1.3239x; 1.3239x over previous
//
#include <hip/hip_runtime.h>

#define BB 512
#define TT 30
#define HH 41
#define WFW 40
#define NSEC 9
#define SECLEN 4
#define NF 50
#define KH 6
#define THRESH 23.0f
#define NBT (BB*TT)                 // 15360 (b,t) rows
#define WIN_CNT (NSEC*BB)           // 4608 winners precede pots in d_out
#define NT_HALF 15                  // t-rows per block (half a batch)
#define ROWF (HH*WFW)               // 1640 floats per (b,t) row
#define SLAB_B 3360                 // bytes/slab: 1680 bf16; 3360%128==32 -> uniform banks
#define XBYTES (NT_HALF*SLAB_B)     // 50400
#define WSW_BYTES (NSEC*4*8*64*16)  // 294912: W as B-fragments, bf16
#define MASK_BYTES (NSEC*BB*2*64*4) // 2359296: u32 half-masks [i][b][h][f64]

typedef __attribute__((ext_vector_type(8))) short short8;   // 8 bf16 = 4 VGPR
typedef __attribute__((ext_vector_type(4))) float f32x4;

// ---------------------------------------------------------------------------
// Pre-kernel: W fp32 -> bf16 B-fragment layout in ws (16x16x32 fragments).
// Fragment (i,nt,kc): lane l holds B[k][f], f = nt*16+(l&15), k = 32kc+8*(l>>4)+j.
// ---------------------------------------------------------------------------
__global__ __launch_bounds__(256) void wconv_kernel(const float* __restrict__ W,
                                                    unsigned char* __restrict__ wsw)
{
    int gid  = blockIdx.x * 256 + threadIdx.x;      // 18432 total
    int frag = gid >> 6, l = gid & 63;
    int i    = frag >> 5, rem = frag & 31;
    int nt   = rem >> 3,  kc  = rem & 7;
    int f    = nt * 16 + (l & 15);
    int kb   = kc * 32 + (l >> 4) * 8;
    unsigned d0 = 0, d1 = 0, d2 = 0, d3 = 0;
    if (f < NF && kb < KH * WFW) {
        const float* src = W + (size_t)(i * NF + f) * (KH * WFW) + kb;
        float4 v0 = ((const float4*)src)[0];
        float4 v1 = ((const float4*)src)[1];
        float vv[8] = {v0.x, v0.y, v0.z, v0.w, v1.x, v1.y, v1.z, v1.w};
        unsigned r[8];
        #pragma unroll
        for (int j = 0; j < 8; ++j) {
            unsigned a = __float_as_uint(vv[j]);
            r[j] = (a + 0x7FFFu + ((a >> 16) & 1u)) >> 16;   // RNE to bf16
        }
        d0 = r[0] | (r[1] << 16); d1 = r[2] | (r[3] << 16);
        d2 = r[4] | (r[5] << 16); d3 = r[6] | (r[7] << 16);
    }
    ((uint4*)wsw)[gid] = make_uint4(d0, d1, d2, d3);
}

// ---------------------------------------------------------------------------
// Main kernel (R8 core, proven): block = (batch b, half h) = 15 t-rows, ALL
// 9 sections. 4 waves; wave nt owns all 4 M-tiles -> 16 independent MFMA
// accumulator chains (the ILP that sets the wall). Ping-pong B prefetch.
// Winners fused via ballot masks. DO NOT TOUCH.
// ---------------------------------------------------------------------------
template<bool WRITE_MASK>
__global__ __launch_bounds__(256, 3) void pots_mfma(const float* __restrict__ x,
                                                    const unsigned char* __restrict__ wsw,
                                                    float* __restrict__ out,
                                                    unsigned* __restrict__ msk)
{
    __shared__ alignas(16) unsigned char xs[XBYTES];            // 50400 B
    __shared__ unsigned long long wsc[NSEC * 4 * 4];            // 1152 B
    const int tid = threadIdx.x;
    const int blk = blockIdx.x;                 // b*2 + h
    const int b   = blk >> 1, h = blk & 1;
    const int bt0 = b * TT + h * NT_HALF;

    // ---- stage 15 full x rows (1640 floats each) -> bf16 slabs, coalesced --
    const float* xg = x + (size_t)bt0 * ROWF;
    #pragma unroll
    for (int it = 0; it < 25; ++it) {
        int idx = tid + it * 256;               // float4 index, 15*410 = 6150
        if (idx < NT_HALF * 410) {
            int r = idx / 410, pos = idx - r * 410;
            const float4 v = *(const float4*)(xg + (size_t)r * ROWF + pos * 4);
            unsigned u0 = __float_as_uint(v.x), u1 = __float_as_uint(v.y);
            unsigned u2 = __float_as_uint(v.z), u3 = __float_as_uint(v.w);
            uint2 p;                            // x in {0,1}: truncation exact
            p.x = (u0 >> 16) | (u1 & 0xFFFF0000u);
            p.y = (u2 >> 16) | (u3 & 0xFFFF0000u);
            *(uint2*)(xs + r * SLAB_B + pos * 8) = p;
        }
    }
    if (tid < 150) {    // zero pad elems 1640..1679 of each slab (K-pad reads)
        int r = tid / 10, part = tid - r * 10;
        *(uint2*)(xs + r * SLAB_B + 3280 + part * 8) = make_uint2(0, 0);
    }
    __syncthreads();

    const int l   = tid & 63, nt = tid >> 6;    // wave id = N-tile
    const int q   = l >> 4;                     // A: k-subblock; D: row-quad
    const int f16 = l & 15;
    const int ff  = nt * 16 + f16;              // global f

    // A base per M-tile: row m = Mt*16 + (l&15); rows 60..63 clamped to 59
    unsigned ab[4];
    #pragma unroll
    for (int Mt = 0; Mt < 4; ++Mt) {
        int m = Mt * 16 + (l & 15); if (m > 59) m = 59;
        ab[Mt] = (unsigned)(m >> 2) * SLAB_B + (unsigned)(m & 3) * 80 + (unsigned)q * 16;
    }
    const unsigned char* wb = wsw + (size_t)nt * 8192 + (size_t)l * 16;

    // ---- ping-pong B-fragment register double-buffer ----
    short8 bf[2][8];
    #pragma unroll
    for (int kc = 0; kc < 8; ++kc)
        bf[0][kc] = *(const short8*)(wb + kc * 1024);

    #pragma unroll
    for (int i = 0; i < NSEC; ++i) {
        const int cur = i & 1, nxt = cur ^ 1;
        if (i < NSEC - 1) {                     // prefetch next section's B
            const unsigned char* wbn = wb + (size_t)(i + 1) * 32768;
            #pragma unroll
            for (int kc = 0; kc < 8; ++kc)
                bf[nxt][kc] = *(const short8*)(wbn + kc * 1024);
        }

        f32x4 acc[4];
        #pragma unroll
        for (int Mt = 0; Mt < 4; ++Mt) acc[Mt] = (f32x4){0.f, 0.f, 0.f, 0.f};

        const unsigned ib = (unsigned)i * 320;  // slab elem 160*i -> +320 B
        #pragma unroll
        for (int kc = 0; kc < 8; ++kc) {
            #pragma unroll
            for (int Mt = 0; Mt < 4; ++Mt) {
                short8 a = *(const short8*)(xs + ab[Mt] + ib + kc * 64);
                acc[Mt] = __builtin_amdgcn_mfma_f32_16x16x32_bf16(a, bf[cur][kc], acc[Mt], 0, 0, 0);
            }
        }

        // D layout: col=f16 (f), rows 4q+reg -> t_loc = Mt*4+q, s = reg
        #pragma unroll
        for (int Mt = 0; Mt < 4; ++Mt) {
            const int t_loc = Mt * 4 + q;
            float m2 = fmaxf(fmaxf(acc[Mt][0], acc[Mt][1]),
                             fmaxf(acc[Mt][2], acc[Mt][3]));
            unsigned long long bal = __ballot(m2 >= THRESH);   // all lanes
            if (WRITE_MASK && l == 0) wsc[(i * 4 + nt) * 4 + Mt] = bal;
            if (t_loc < NT_HALF && ff < NF) {
                size_t o = ((size_t)i * NBT + bt0 + t_loc) * NF + ff;
                *(float4*)(out + WIN_CNT + o * 4) =
                    make_float4(acc[Mt][0], acc[Mt][1], acc[Mt][2], acc[Mt][3]);
            }
        }
    }

    if (WRITE_MASK) {
        __syncthreads();
        // assemble 15-bit t-mask per (i, f) and store u32 half-mask
        #pragma unroll
        for (int it = 0; it < 3; ++it) {
            int idx = tid + it * 256;           // 9*64 = 576 entries
            if (idx < NSEC * 64) {
                int i  = idx >> 6, f = idx & 63;
                int ng = f >> 4,  fl = f & 15;
                unsigned m = 0;
                #pragma unroll
                for (int Mt = 0; Mt < 4; ++Mt) {
                    unsigned long long w =
                        (wsc[(i * 4 + ng) * 4 + Mt] >> fl) & 0x0001000100010001ULL;
                    unsigned bq = (unsigned)((w | (w >> 15) | (w >> 30) | (w >> 45)) & 0xFULL);
                    m |= bq << (Mt * 4);        // bit t_loc = Mt*4 + q
                }
                m &= 0x7FFFu;                   // drop clamped t_loc = 15
                msk[((size_t)(i * BB + b) * 2 + h) * 64 + f] = m;
            }
        }
    }
}

// ---------------------------------------------------------------------------
// Winners from half-masks — 256-thread blocks, 4 (i,b) pairs each (grid
// 4608 -> 1152 dispatched blocks; win path was launch/dispatch-bound).
// Verified formula: c=popcnt, first=min(30-c,29), fv=bit(first),
// total=c*(fv+30*any(fv)), first-occurrence argmax, -1 if total<=0.
// ---------------------------------------------------------------------------
__global__ __launch_bounds__(256) void win_msk(const unsigned* __restrict__ msk,
                                               float* __restrict__ out)
{
    const int sub = threadIdx.x >> 6;        // 0..3
    const int f   = threadIdx.x & 63;
    const int blk = blockIdx.x * 4 + sub;    // i*BB + b
    unsigned m0 = msk[(size_t)blk * 128 + f];
    unsigned m1 = msk[(size_t)blk * 128 + 64 + f];
    unsigned mask = m0 | (m1 << 15);         // 30 t-bits
    int c     = __popc(mask);
    int first = TT - c; if (first > TT - 1) first = TT - 1;
    int fv    = (f < NF) ? (int)((mask >> first) & 1u) : 0;
    unsigned long long bal = __ballot(fv != 0);
    int v30 = (bal != 0ull) ? TT : 0;
    int tot = (f < NF) ? c * (fv + v30) : -1;
    int idx = f;
    for (int off = 32; off > 0; off >>= 1) {
        int ot = __shfl_xor(tot, off);
        int oi = __shfl_xor(idx, off);
        if (ot > tot || (ot == tot && oi < idx)) { tot = ot; idx = oi; }
    }
    if (f == 0) out[blk] = (float)((tot > 0) ? idx : -1);
}

// Fallback: winners straight from pots (if ws too small for mask buffer).
__global__ __launch_bounds__(64) void win_pots(float* __restrict__ out)
{
    const int blk = blockIdx.x;
    const int f   = threadIdx.x;
    const float* po = out + WIN_CNT + (size_t)blk * TT * NF * SECLEN;
    unsigned mask = 0u;
    if (f < NF) {
        for (int t = 0; t < TT; ++t) {
            const float4 v = *(const float4*)(po + ((size_t)t * NF + f) * SECLEN);
            float m = fmaxf(fmaxf(v.x, v.y), fmaxf(v.z, v.w));
            if (m >= THRESH) mask |= (1u << t);
        }
    }
    int c     = __popc(mask);
    int first = TT - c; if (first > TT - 1) first = TT - 1;
    int fv    = (f < NF) ? (int)((mask >> first) & 1u) : 0;
    unsigned long long bal = __ballot(fv != 0);
    int v30 = (bal != 0ull) ? TT : 0;
    int tot = (f < NF) ? c * (fv + v30) : -1;
    int idx = f;
    for (int off = 32; off > 0; off >>= 1) {
        int ot = __shfl_xor(tot, off);
        int oi = __shfl_xor(idx, off);
        if (ot > tot || (ot == tot && oi < idx)) { tot = ot; idx = oi; }
    }
    if (f == 0) out[blk] = (float)((tot > 0) ? idx : -1);
}

extern "C" void kernel_launch(void* const* d_in, const int* in_sizes, int n_in,
                              void* d_out, int out_size, void* d_ws, size_t ws_size,
                              hipStream_t stream)
{
    const float* x = (const float*)d_in[0];
    const float* W = (const float*)d_in[1];
    float* out = (float*)d_out;
    unsigned char* wsw = (unsigned char*)d_ws;
    unsigned* msk = (unsigned*)(wsw + WSW_BYTES);
    const bool use_msk = ws_size >= (size_t)(WSW_BYTES + MASK_BYTES);

    wconv_kernel<<<(NSEC*4*8*64) / 256, 256, 0, stream>>>(W, wsw);
    if (use_msk) {
        pots_mfma<true><<<BB * 2, 256, 0, stream>>>(x, wsw, out, msk);
        win_msk<<<(NSEC * BB) / 4, 256, 0, stream>>>(msk, out);
    } else {
        pots_mfma<false><<<BB * 2, 256, 0, stream>>>(x, wsw, out, nullptr);
        win_pots<<<NSEC * BB, 64, 0, stream>>>(out);
    }
}